// Round 3
// baseline (777.909 us; speedup 1.0000x reference)
//
#include <hip/hip_runtime.h>
#include <math.h>

// Problem constants: [b, seq, heads, head_dim] = [4, 8192, 16, 64], f32.
#define BB 4
#define SS 8192
#define HH 16

// ws layout (floats):
//   [0, 6144)        sums[3][4][8][64]   (group, batch, qh(padded to 8), d)
//   X0 @ 6144        [4][8192][6][64]    group 0 pre-norm x
//   X1 after X0      [4][4096][5][64]    group 1
//   X2 after X1      [4][2048][5][64]    group 2
//   PART after X2    per-block partial sums [7168][384]   (full path only)
static const long X0_OFF = 6144;
static const long X0_SZ = 4L * 8192 * 6 * 64;
static const long X1_OFF = X0_OFF + X0_SZ;
static const long X1_SZ = 4L * 4096 * 5 * 64;
static const long X2_OFF = X1_OFF + X1_SZ;
static const long X2_SZ = 4L * 2048 * 5 * 64;
static const long PART_OFF = X2_OFF + X2_SZ;
static const long SZP0 = 4L * 1024 * 384;   // group-0 partials
static const long SZP1 = 4L * 512 * 384;    // group-1
static const long SZP2 = 4L * 256 * 384;    // group-2
static const long WS_SMALL = PART_OFF;                       // atomic fallback
static const long WS_FULL  = PART_OFF + SZP0 + SZP1 + SZP2;  // ~92.9 MB

__global__ __launch_bounds__(256) void k_zero_sums(float* ws) {
    int idx = blockIdx.x * 256 + threadIdx.x;
    if (idx < 6144) ws[idx] = 0.0f;
}

// Pass 1 (rewritten): LDS-staged, shuffle-free, flat parallel phases.
// Block = 256 threads handles P=8 positions of one dilation group.
//   Phase L: stage Q,K rows into LDS (row stride 68 floats -> bank rotation)
//   Phase S: thread-per-(pos,qh,kh) 64-d dot from LDS (288/200 independent)
//   Phase M: thread-per-(pos,qh) softmax in LDS
//   Phase V: thread-per-(pos,qh,d4) PV; V read from global (L1 broadcast);
//            X stored; per-block psum via LDS atomics
//   Tail: dense per-block partial store (full path) or global atomics (fallback)
template<int G, int LTPB, int RR, int OFFS, int HMIN, int JJ, bool ATOMIC>
__global__ __launch_bounds__(256) void k_attn2(const float* __restrict__ Q,
                                               const float* __restrict__ K,
                                               const float* __restrict__ V,
                                               float* __restrict__ ws,
                                               long xoff, long pbase, int gi) {
    constexpr int P = 8;
    constexpr int ROWS = P * G;        // 48 (g0) or 40 (g1/g2)
    constexpr int STR = 17;            // float4 stride per LDS row (68 floats)
    __shared__ __align__(16) float lq[ROWS * STR * 4];
    __shared__ __align__(16) float lk[ROWS * STR * 4];
    __shared__ float sc[P * G * G];    // scores -> softmax probs (in place)
    __shared__ float psum[384];        // per-block sum over pos of x

    const int t = threadIdx.x;
    const int bid = blockIdx.x;
    const int b = bid >> LTPB;
    const int tile = bid & ((1 << LTPB) - 1);
    const int j0 = tile * P;

    for (int i = t; i < 384; i += 256) psum[i] = 0.0f;

    // ---- Phase L: stage Q,K rows (coalesced float4 global -> LDS) ----
    for (int e = t; e < ROWS * 16; e += 256) {
        const int row = e >> 4, d4 = e & 15;
        const int pos = row / G, hh = row - pos * G;   // row = pos*G + hh
        const long g16 = (((long)b * SS + OFFS + (long)(j0 + pos) * RR) * HH + HMIN + hh) * 16;
        float4 qv = ((const float4*)Q)[g16 + d4];
        float4 kv = ((const float4*)K)[g16 + d4];
        *(float4*)&lq[(row * STR + d4) * 4] = qv;
        *(float4*)&lk[(row * STR + d4) * 4] = kv;
    }
    __syncthreads();

    // ---- Phase S: independent 64-d dots, one per (pos,qh,kh) ----
    for (int it = t; it < P * G * G; it += 256) {
        const int pos = it / (G * G);
        const int rem = it - pos * (G * G);
        const int qh = rem / G, kh = rem - (rem / G) * G;
        const float4* qr = (const float4*)&lq[(pos * G + qh) * STR * 4];
        const float4* kr = (const float4*)&lk[(pos * G + kh) * STR * 4];
        float4 a = make_float4(0.f, 0.f, 0.f, 0.f);
#pragma unroll
        for (int d4 = 0; d4 < 16; ++d4) {
            float4 x = qr[d4], y = kr[d4];
            a.x += x.x * y.x; a.y += x.y * y.y;
            a.z += x.z * y.z; a.w += x.w * y.w;
        }
        sc[it] = (a.x + a.y) + (a.z + a.w);
    }
    __syncthreads();

    // ---- Phase M: softmax over kh per (pos,qh) ----
    if (t < P * G) {
        float* row = &sc[t * G];
        float mx = row[0];
#pragma unroll
        for (int k2 = 1; k2 < G; ++k2) mx = fmaxf(mx, row[k2]);
        float e_[G];
        float den = 0.f;
#pragma unroll
        for (int k2 = 0; k2 < G; ++k2) {
            e_[k2] = __expf((row[k2] - mx) * 0.125f);
            den += e_[k2];
        }
        const float rd = __frcp_rn(den);
#pragma unroll
        for (int k2 = 0; k2 < G; ++k2) row[k2] = e_[k2] * rd;
    }
    __syncthreads();

    // ---- Phase V: x = attn @ V ; store X; accumulate block psum ----
    for (int it = t; it < P * G * 16; it += 256) {
        const int pos = it / (G * 16);
        const int rem = it - pos * (G * 16);
        const int qh = rem >> 4, d4 = rem & 15;
        const long vrow16 = (((long)b * SS + OFFS + (long)(j0 + pos) * RR) * HH + HMIN) * 16;
        const float* pr = &sc[(pos * G + qh) * G];
        float4 acc = make_float4(0.f, 0.f, 0.f, 0.f);
#pragma unroll
        for (int kh = 0; kh < G; ++kh) {
            float4 v4 = ((const float4*)V)[vrow16 + kh * 16 + d4];   // 16-lane 256B, L1 broadcast over qh
            const float pw = pr[kh];
            acc.x += pw * v4.x; acc.y += pw * v4.y;
            acc.z += pw * v4.z; acc.w += pw * v4.w;
        }
        ((float4*)(ws + xoff))[((long)(b * JJ + j0 + pos) * G + qh) * 16 + d4] = acc;
        const int pb = (qh * 16 + d4) * 4;
        atomicAdd(&psum[pb + 0], acc.x);
        atomicAdd(&psum[pb + 1], acc.y);
        atomicAdd(&psum[pb + 2], acc.z);
        atomicAdd(&psum[pb + 3], acc.w);
    }
    __syncthreads();

    if (ATOMIC) {
        for (int i = t; i < G * 64; i += 256)
            unsafeAtomicAdd(ws + (long)(gi * 4 + b) * 512 + i, psum[i]);
    } else {
        // dense store: partial slot == bid (bid = b*TPB + tile)
        float* dst = ws + pbase + (long)bid * 384;
        for (int i = t; i < 384; i += 256) dst[i] = psum[i];
    }
}

// Reduce per-block partials into sums[3][4][8][64]. 4608 threads; coalesced.
__global__ __launch_bounds__(256) void k_sums(float* __restrict__ ws) {
    const int o = blockIdx.x * 256 + threadIdx.x;
    if (o >= 4608) return;                  // 3 groups * 4 batches * 384
    const int gi = o / 1536;
    const int rem = o - gi * 1536;
    const int b = rem / 384;
    const int s = rem - b * 384;
    const int nslots = 1024 >> gi;          // 1024 / 512 / 256 tiles per batch
    const long gb = (gi == 0) ? 0 : ((gi == 1) ? SZP0 : (SZP0 + SZP1));
    long base = PART_OFF + gb + ((long)b * nslots) * 384 + s;
    float acc = 0.f;
    for (int k2 = 0; k2 < nslots; ++k2) acc += ws[base + (long)k2 * 384];
    ws[(long)(gi * 4 + b) * 512 + s] = acc;
}

// Pass 2: gather + normalize (unchanged from round-2; it improved there).
__global__ __launch_bounds__(256) void k_out(const float* __restrict__ ws,
                                             float* __restrict__ out) {
    const int t = threadIdx.x;
    const int bid = blockIdx.x;
    const int dd4 = t & 15;
    const int h = t >> 4;
    const int b = bid >> 10;           // 1024 position-blocks per batch
    const int pos0 = (bid & 1023) * 8;

    const bool has0 = (h < 6);
    const bool has1 = (h >= 5 && h <= 9);
    const bool has2 = (h >= 10 && h <= 14);

    float4 rs0 = make_float4(1.f, 1.f, 1.f, 1.f), rs1 = rs0, rs2 = rs0;
    if (has0) rs0 = ((const float4*)(ws + ((long)(0 * 4 + b) * 8 + h) * 64))[dd4];
    if (has1) rs1 = ((const float4*)(ws + ((long)(1 * 4 + b) * 8 + (h - 5)) * 64))[dd4];
    if (has2) rs2 = ((const float4*)(ws + ((long)(2 * 4 + b) * 8 + (h - 10)) * 64))[dd4];

    float4 x0[8], x1[4], x2[2];
    if (has0) {
#pragma unroll
        for (int pp = 0; pp < 8; ++pp)
            x0[pp] = ((const float4*)(ws + X0_OFF + (((long)b * 8192 + pos0 + pp) * 6 + h) * 64))[dd4];
    }
    if (has1) {
#pragma unroll
        for (int q = 0; q < 4; ++q) {
            int jj = (pos0 >> 1) + q;
            x1[q] = ((const float4*)(ws + X1_OFF + (((long)b * 4096 + jj) * 5 + (h - 5)) * 64))[dd4];
        }
    }
    if (has2) {
#pragma unroll
        for (int q = 0; q < 2; ++q) {
            int jj = (pos0 >> 2) + q;
            x2[q] = ((const float4*)(ws + X2_OFF + (((long)b * 2048 + jj) * 5 + (h - 10)) * 64))[dd4];
        }
    }

    if (has0) { rs0.x = __frcp_rn(rs0.x); rs0.y = __frcp_rn(rs0.y); rs0.z = __frcp_rn(rs0.z); rs0.w = __frcp_rn(rs0.w); }
    if (has1) { rs1.x = __frcp_rn(rs1.x); rs1.y = __frcp_rn(rs1.y); rs1.z = __frcp_rn(rs1.z); rs1.w = __frcp_rn(rs1.w); }
    if (has2) { rs2.x = __frcp_rn(rs2.x); rs2.y = __frcp_rn(rs2.y); rs2.z = __frcp_rn(rs2.z); rs2.w = __frcp_rn(rs2.w); }

    const float third = 1.0f / 3.0f;
#pragma unroll
    for (int pp = 0; pp < 8; ++pp) {
        float4 r = make_float4(0.f, 0.f, 0.f, 0.f);

        if (has0) {
            r.x += x0[pp].x * rs0.x; r.y += x0[pp].y * rs0.y;
            r.z += x0[pp].z * rs0.z; r.w += x0[pp].w * rs0.w;
        }
        if (has1 && (pp & 1) == 1) {
            int q = pp >> 1;
            r.x += x1[q].x * rs1.x; r.y += x1[q].y * rs1.y;
            r.z += x1[q].z * rs1.z; r.w += x1[q].w * rs1.w;
        }
        if (has2 && (pp & 3) == 2) {
            int q = pp >> 2;
            r.x += x2[q].x * rs2.x; r.y += x2[q].y * rs2.y;
            r.z += x2[q].z * rs2.z; r.w += x2[q].w * rs2.w;
        }

        r.x *= third; r.y *= third; r.z *= third; r.w *= third;
        ((float4*)out)[((long)(b * 8192 + pos0 + pp)) * 256 + t] = r;
    }
}

extern "C" void kernel_launch(void* const* d_in, const int* in_sizes, int n_in,
                              void* d_out, int out_size, void* d_ws, size_t ws_size,
                              hipStream_t stream) {
    const float* Q = (const float*)d_in[0];
    const float* K = (const float*)d_in[1];
    const float* V = (const float*)d_in[2];
    float* ws = (float*)d_ws;
    float* out = (float*)d_out;

    const bool full = ws_size >= (size_t)WS_FULL * sizeof(float);
    if (!full && ws_size < (size_t)WS_SMALL * sizeof(float)) return;

    if (full) {
        // no-atomic path: per-block partial store + small reduction
        k_attn2<6, 10, 1, 0, 0,  8192, false><<<4096, 256, 0, stream>>>(Q, K, V, ws, X0_OFF, PART_OFF, 0);
        k_attn2<5, 9,  2, 1, 5,  4096, false><<<2048, 256, 0, stream>>>(Q, K, V, ws, X1_OFF, PART_OFF + SZP0, 1);
        k_attn2<5, 8,  4, 2, 10, 2048, false><<<1024, 256, 0, stream>>>(Q, K, V, ws, X2_OFF, PART_OFF + SZP0 + SZP1, 2);
        k_sums<<<18, 256, 0, stream>>>(ws);
    } else {
        // fallback: global atomics into zeroed sums region
        k_zero_sums<<<24, 256, 0, stream>>>(ws);
        k_attn2<6, 10, 1, 0, 0,  8192, true><<<4096, 256, 0, stream>>>(Q, K, V, ws, X0_OFF, 0, 0);
        k_attn2<5, 9,  2, 1, 5,  4096, true><<<2048, 256, 0, stream>>>(Q, K, V, ws, X1_OFF, 0, 1);
        k_attn2<5, 8,  4, 2, 10, 2048, true><<<1024, 256, 0, stream>>>(Q, K, V, ws, X2_OFF, 0, 2);
    }
    k_out<<<4096, 256, 0, stream>>>(ws, out);
}

// Round 4
// 410.921 us; speedup vs baseline: 1.8931x; 1.8931x over previous
//
#include <hip/hip_runtime.h>
#include <math.h>

// Problem constants: [b, seq, heads, head_dim] = [4, 8192, 16, 64], f32.
#define BB 4
#define SS 8192
#define HH 16

// ws layout (floats):
//   [0, 6144)        sums[3][4][8][64]   (group, batch, qh(padded to 8), d)
//   X0 @ 6144        [4][8192][6][64]    group 0 pre-norm x
//   X1 after X0      [4][4096][5][64]    group 1
//   X2 after X1      [4][2048][5][64]    group 2
static const long X0_OFF = 6144;
static const long X0_SZ = 4L * 8192 * 6 * 64;
static const long X1_OFF = X0_OFF + X0_SZ;
static const long X1_SZ = 4L * 4096 * 5 * 64;
static const long X2_OFF = X1_OFF + X1_SZ;
static const long X2_SZ = 4L * 2048 * 5 * 64;
static const long WS_FLOATS = X2_OFF + X2_SZ;   // ~20.45M floats = 81.8 MB

__global__ __launch_bounds__(256) void k_zero_sums(float* ws) {
    int idx = blockIdx.x * 256 + threadIdx.x;
    if (idx < 6144) ws[idx] = 0.0f;
}

// Pass 1: LDS-staged, shuffle-free, flat parallel phases. One block = 8
// positions of one dilation group. Single launch, compile-time dispatch.
//   L: stage Q,K rows to LDS (STR=17 float4/row -> 2-way conflicts max, free)
//   S: thread-per-(pos,qh,kh) 64-d dot from LDS (288/200 independent dots)
//   M: thread-per-(pos,qh) softmax in LDS
//   V: thread-per-(pos,qh,d4) PV from global V (L1-broadcast); store X to ws
//      AND to xbuf (aliases dead lq region)
//   T: thread-per-(qh,d) sums xbuf over pos (no atomics in LDS), then ONE
//      global unsafeAtomicAdd per (qh,d) per block (proven cheap in r0-r2).
template<int G, int RR, int OFFS, int HMIN, int JJ>
__device__ __forceinline__ void attn_body(const float* __restrict__ Q,
                                          const float* __restrict__ K,
                                          const float* __restrict__ V,
                                          float* __restrict__ ws,
                                          float* buf, int b, int tile, int gi,
                                          long xoff) {
    constexpr int P = 8;
    constexpr int ROWS = P * G;        // 48 (g0) or 40 (g1/g2)
    constexpr int STR = 17;            // float4 stride per LDS row (68 floats)
    float* lq = buf;                               // ROWS*STR*4 floats
    float* lk = buf + ROWS * STR * 4;              // ROWS*STR*4 floats
    float* sc = lk + ROWS * STR * 4;               // P*G*G floats
    float* xbuf = buf;                             // aliases lq (dead after S)

    const int t = threadIdx.x;
    const int j0 = tile * P;

    // ---- Phase L: stage Q,K rows (coalesced float4 global -> LDS) ----
    for (int e = t; e < ROWS * 16; e += 256) {
        const int row = e >> 4, d4 = e & 15;
        const int pos = row / G, hh = row - pos * G;
        const long g16 = (((long)b * SS + OFFS + (long)(j0 + pos) * RR) * HH + HMIN + hh) * 16;
        float4 qv = ((const float4*)Q)[g16 + d4];
        float4 kv = ((const float4*)K)[g16 + d4];
        *(float4*)&lq[(row * STR + d4) * 4] = qv;
        *(float4*)&lk[(row * STR + d4) * 4] = kv;
    }
    __syncthreads();

    // ---- Phase S: independent 64-d dots, one per (pos,qh,kh) ----
    for (int it = t; it < P * G * G; it += 256) {
        const int pos = it / (G * G);
        const int rem = it - pos * (G * G);
        const int qh = rem / G, kh = rem - (rem / G) * G;
        const float4* qr = (const float4*)&lq[(pos * G + qh) * STR * 4];
        const float4* kr = (const float4*)&lk[(pos * G + kh) * STR * 4];
        float4 a = make_float4(0.f, 0.f, 0.f, 0.f);
#pragma unroll
        for (int d4 = 0; d4 < 16; ++d4) {
            float4 x = qr[d4], y = kr[d4];
            a.x += x.x * y.x; a.y += x.y * y.y;
            a.z += x.z * y.z; a.w += x.w * y.w;
        }
        sc[it] = (a.x + a.y) + (a.z + a.w);
    }
    __syncthreads();

    // ---- Phase M: softmax over kh per (pos,qh) ----
    if (t < P * G) {
        float* row = &sc[t * G];
        float mx = row[0];
#pragma unroll
        for (int k2 = 1; k2 < G; ++k2) mx = fmaxf(mx, row[k2]);
        float e_[G];
        float den = 0.f;
#pragma unroll
        for (int k2 = 0; k2 < G; ++k2) {
            e_[k2] = __expf((row[k2] - mx) * 0.125f);
            den += e_[k2];
        }
        const float rd = __frcp_rn(den);
#pragma unroll
        for (int k2 = 0; k2 < G; ++k2) row[k2] = e_[k2] * rd;
    }
    __syncthreads();   // after this, lq/lk are dead -> xbuf may overwrite

    // ---- Phase V: x = attn @ V ; store X to ws and xbuf ----
    for (int it = t; it < P * G * 16; it += 256) {
        const int pos = it / (G * 16);
        const int rem = it - pos * (G * 16);
        const int qh = rem >> 4, d4 = rem & 15;
        const long vrow16 = (((long)b * SS + OFFS + (long)(j0 + pos) * RR) * HH + HMIN) * 16;
        const float* pr = &sc[(pos * G + qh) * G];
        float4 acc = make_float4(0.f, 0.f, 0.f, 0.f);
#pragma unroll
        for (int kh = 0; kh < G; ++kh) {
            float4 v4 = ((const float4*)V)[vrow16 + kh * 16 + d4];  // 256B/16-lane, L1 reuse
            const float pw = pr[kh];
            acc.x += pw * v4.x; acc.y += pw * v4.y;
            acc.z += pw * v4.z; acc.w += pw * v4.w;
        }
        ((float4*)(ws + xoff))[((long)(b * JJ + j0 + pos) * G + qh) * 16 + d4] = acc;
        *(float4*)&xbuf[pos * (G * 64) + qh * 64 + d4 * 4] = acc;
    }
    __syncthreads();

    // ---- Phase T: sum over pos (conflict-free strided LDS reads), 1 atomic ----
    for (int s = t; s < G * 64; s += 256) {
        float a = 0.f;
#pragma unroll
        for (int pos = 0; pos < P; ++pos) a += xbuf[pos * (G * 64) + s];
        unsafeAtomicAdd(ws + (long)(gi * 4 + b) * 512 + s, a);
    }
}

__global__ __launch_bounds__(256) void k_attn3(const float* __restrict__ Q,
                                               const float* __restrict__ K,
                                               const float* __restrict__ V,
                                               float* __restrict__ ws) {
    __shared__ __align__(16) float buf[6816];  // max over groups (g0: 27.3 KB)
    const int bid = blockIdx.x;
    if (bid < 4096) {
        attn_body<6, 1, 0, 0, 8192>(Q, K, V, ws, buf, bid >> 10, bid & 1023, 0, X0_OFF);
    } else if (bid < 6144) {
        const int r2 = bid - 4096;
        attn_body<5, 2, 1, 5, 4096>(Q, K, V, ws, buf, r2 >> 9, r2 & 511, 1, X1_OFF);
    } else {
        const int r2 = bid - 6144;
        attn_body<5, 4, 2, 10, 2048>(Q, K, V, ws, buf, r2 >> 8, r2 & 255, 2, X2_OFF);
    }
}

// Pass 2: gather + normalize (unchanged; improved in r2 and stayed out of top-5).
__global__ __launch_bounds__(256) void k_out(const float* __restrict__ ws,
                                             float* __restrict__ out) {
    const int t = threadIdx.x;
    const int bid = blockIdx.x;
    const int dd4 = t & 15;
    const int h = t >> 4;
    const int b = bid >> 10;           // 1024 position-blocks per batch
    const int pos0 = (bid & 1023) * 8;

    const bool has0 = (h < 6);
    const bool has1 = (h >= 5 && h <= 9);
    const bool has2 = (h >= 10 && h <= 14);

    float4 rs0 = make_float4(1.f, 1.f, 1.f, 1.f), rs1 = rs0, rs2 = rs0;
    if (has0) rs0 = ((const float4*)(ws + ((long)(0 * 4 + b) * 8 + h) * 64))[dd4];
    if (has1) rs1 = ((const float4*)(ws + ((long)(1 * 4 + b) * 8 + (h - 5)) * 64))[dd4];
    if (has2) rs2 = ((const float4*)(ws + ((long)(2 * 4 + b) * 8 + (h - 10)) * 64))[dd4];

    float4 x0[8], x1[4], x2[2];
    if (has0) {
#pragma unroll
        for (int pp = 0; pp < 8; ++pp)
            x0[pp] = ((const float4*)(ws + X0_OFF + (((long)b * 8192 + pos0 + pp) * 6 + h) * 64))[dd4];
    }
    if (has1) {
#pragma unroll
        for (int q = 0; q < 4; ++q) {
            int jj = (pos0 >> 1) + q;
            x1[q] = ((const float4*)(ws + X1_OFF + (((long)b * 4096 + jj) * 5 + (h - 5)) * 64))[dd4];
        }
    }
    if (has2) {
#pragma unroll
        for (int q = 0; q < 2; ++q) {
            int jj = (pos0 >> 2) + q;
            x2[q] = ((const float4*)(ws + X2_OFF + (((long)b * 2048 + jj) * 5 + (h - 10)) * 64))[dd4];
        }
    }

    if (has0) { rs0.x = __frcp_rn(rs0.x); rs0.y = __frcp_rn(rs0.y); rs0.z = __frcp_rn(rs0.z); rs0.w = __frcp_rn(rs0.w); }
    if (has1) { rs1.x = __frcp_rn(rs1.x); rs1.y = __frcp_rn(rs1.y); rs1.z = __frcp_rn(rs1.z); rs1.w = __frcp_rn(rs1.w); }
    if (has2) { rs2.x = __frcp_rn(rs2.x); rs2.y = __frcp_rn(rs2.y); rs2.z = __frcp_rn(rs2.z); rs2.w = __frcp_rn(rs2.w); }

    const float third = 1.0f / 3.0f;
#pragma unroll
    for (int pp = 0; pp < 8; ++pp) {
        float4 r = make_float4(0.f, 0.f, 0.f, 0.f);

        if (has0) {
            r.x += x0[pp].x * rs0.x; r.y += x0[pp].y * rs0.y;
            r.z += x0[pp].z * rs0.z; r.w += x0[pp].w * rs0.w;
        }
        if (has1 && (pp & 1) == 1) {
            int q = pp >> 1;
            r.x += x1[q].x * rs1.x; r.y += x1[q].y * rs1.y;
            r.z += x1[q].z * rs1.z; r.w += x1[q].w * rs1.w;
        }
        if (has2 && (pp & 3) == 2) {
            int q = pp >> 2;
            r.x += x2[q].x * rs2.x; r.y += x2[q].y * rs2.y;
            r.z += x2[q].z * rs2.z; r.w += x2[q].w * rs2.w;
        }

        r.x *= third; r.y *= third; r.z *= third; r.w *= third;
        ((float4*)out)[((long)(b * 8192 + pos0 + pp)) * 256 + t] = r;
    }
}

extern "C" void kernel_launch(void* const* d_in, const int* in_sizes, int n_in,
                              void* d_out, int out_size, void* d_ws, size_t ws_size,
                              hipStream_t stream) {
    const float* Q = (const float*)d_in[0];
    const float* K = (const float*)d_in[1];
    const float* V = (const float*)d_in[2];
    float* ws = (float*)d_ws;
    float* out = (float*)d_out;

    if (ws_size < (size_t)WS_FLOATS * sizeof(float)) return;  // need ~82 MB scratch

    k_zero_sums<<<24, 256, 0, stream>>>(ws);
    k_attn3<<<7168, 256, 0, stream>>>(Q, K, V, ws);
    k_out<<<4096, 256, 0, stream>>>(ws, out);
}

// Round 5
// 395.988 us; speedup vs baseline: 1.9645x; 1.0377x over previous
//
#include <hip/hip_runtime.h>
#include <math.h>

// Problem constants: [b, seq, heads, head_dim] = [4, 8192, 16, 64], f32.
#define BB 4
#define SS 8192
#define HH 16
#define DDIM 64

// ws layout (floats):
//   [0, 6144)        sums[3][4][8][64]   (group, batch, qh(padded to 8), d)
//   X0 @ 6144        [4][8192][6][64]    group 0 pre-norm x
//   X1 after X0      [4][4096][5][64]    group 1
//   X2 after X1      [4][2048][5][64]    group 2
static const long X0_OFF = 6144;
static const long X0_SZ = 4L * 8192 * 6 * 64;
static const long X1_OFF = X0_OFF + X0_SZ;
static const long X1_SZ = 4L * 4096 * 5 * 64;
static const long X2_OFF = X1_OFF + X1_SZ;
static const long X2_SZ = 4L * 2048 * 5 * 64;
static const long WS_FLOATS = X2_OFF + X2_SZ;   // ~20.45M floats = 81.8 MB

__global__ __launch_bounds__(256) void k_zero_sums(float* ws) {
    int idx = blockIdx.x * 256 + threadIdx.x;
    if (idx < 6144) ws[idx] = 0.0f;
}

__device__ __forceinline__ float4 shfl_xor4(float4 v, int m) {
    return make_float4(__shfl_xor(v.x, m, 64), __shfl_xor(v.y, m, 64),
                       __shfl_xor(v.z, m, 64), __shfl_xor(v.w, m, 64));
}

// DPP row-rotate add: v += rotate_within_16lane_row(v, N). VALU pipe only —
// replaces ds_swizzle-based __shfl_xor for the 16-lane d-reduction.
// dpp_ctrl: row_ror:N = 0x120|N.
template<int CTRL>
__device__ __forceinline__ float dpp_ror_add(float v) {
    int r = __builtin_amdgcn_update_dpp(0, __float_as_int(v), CTRL, 0xF, 0xF, true);
    return v + __int_as_float(r);
}
// Full 16-lane row sum, result in every lane of the row. 4 VALU ops, ~16 cy.
__device__ __forceinline__ float rowsum16(float v) {
    v = dpp_ror_add<0x128>(v);   // + ror 8
    v = dpp_ror_add<0x124>(v);   // + ror 4
    v = dpp_ror_add<0x122>(v);   // + ror 2
    v = dpp_ror_add<0x121>(v);   // + ror 1
    return v;
}

// Pass 1: per-position head-group attention (r0 structure — best measured at
// 109 us — with the score reduction moved from ds_swizzle shuffles to DPP
// row_ror VALU adds; everything else byte-for-byte the r0 algorithm).
// Lane layout: lane = (posInWave<<4) | d4 -> 16 lanes own one position's 64-d.
__global__ __launch_bounds__(256) void k_attn(const float* __restrict__ Q,
                                              const float* __restrict__ Kp,
                                              const float* __restrict__ Vp,
                                              float* __restrict__ ws) {
    __shared__ __align__(16) float psum[4][6][64];  // wave, qh, d

    int bid = blockIdx.x;
    int gi, b, tile, g, r, off, hmin, J;
    long xoff;
    if (bid < 2048)      { gi = 0; b = bid >> 9; tile = bid & 511; g = 6; r = 1; off = 0; hmin = 0;  J = 8192; xoff = X0_OFF; }
    else if (bid < 3072) { gi = 1; bid -= 2048; b = bid >> 8; tile = bid & 255; g = 5; r = 2; off = 1; hmin = 5;  J = 4096; xoff = X1_OFF; }
    else                 { gi = 2; bid -= 3072; b = bid >> 7; tile = bid & 127; g = 5; r = 4; off = 2; hmin = 10; J = 2048; xoff = X2_OFF; }

    const int t = threadIdx.x;
    const int lane = t & 63;
    const int wave = t >> 6;
    const int d4 = t & 15;          // which float4 of the 64-d row
    const int pIdx = t >> 4;        // position within block (0..15)
    const int j = tile * 16 + pIdx; // strided-view position index
    const int pos = off + j * r;    // real sequence position

    const long rowbase = (((long)b * SS + pos) * HH + hmin) * DDIM;
    const float4* q4p = (const float4*)(Q + rowbase);
    const float4* k4p = (const float4*)(Kp + rowbase);
    const float4* v4p = (const float4*)(Vp + rowbase);

    // Dense loads: lane d4 reads float4 #d4 of each head row (256B/16-lane burst)
    float4 q4[6], k4[6], v4[6];
#pragma unroll
    for (int hh = 0; hh < 6; ++hh) {
        if (hh < g) {
            q4[hh] = q4p[hh * 16 + d4];
            k4[hh] = k4p[hh * 16 + d4];
            v4[hh] = v4p[hh * 16 + d4];
        } else {
            q4[hh] = make_float4(0.f, 0.f, 0.f, 0.f);
            k4[hh] = q4[hh];
            v4[hh] = q4[hh];
        }
    }

    // scores p[qh][kh] = q_qh . k_kh : per-lane partial dot + DPP row-sum.
    // The reduction is pure VALU (row_ror adds) — no LDS-pipe shuffles.
    float p[6][6];
#pragma unroll
    for (int qh = 0; qh < 6; ++qh) {
#pragma unroll
        for (int kh = 0; kh < 6; ++kh) {
            if (qh < g && kh < g) {
                float s = q4[qh].x * k4[kh].x + q4[qh].y * k4[kh].y +
                          q4[qh].z * k4[kh].z + q4[qh].w * k4[kh].w;
                p[qh][kh] = rowsum16(s);
            } else {
                p[qh][kh] = 0.0f;
            }
        }
    }

    // softmax over kh per qh (duplicated across the 16 d4 lanes; cheap)
#pragma unroll
    for (int qh = 0; qh < 6; ++qh) {
        if (qh >= g) continue;
        float mx = -3.4e38f;
#pragma unroll
        for (int kh = 0; kh < 6; ++kh)
            if (kh < g) mx = fmaxf(mx, p[qh][kh]);
        float den = 0.0f;
#pragma unroll
        for (int kh = 0; kh < 6; ++kh) {
            if (kh < g) { p[qh][kh] = __expf((p[qh][kh] - mx) * 0.125f); den += p[qh][kh]; }
        }
        float rden = 1.0f / den;
#pragma unroll
        for (int kh = 0; kh < 6; ++kh) p[qh][kh] *= rden;
    }

    // x = attn @ V ; dense 256B stores; shfl_xor over 4 positions for norm sum
    float4* xrow = (float4*)(ws + xoff + (((long)b * J + j) * g) * DDIM);
#pragma unroll
    for (int qh = 0; qh < 6; ++qh) {
        if (qh >= g) continue;
        float4 o = make_float4(0.f, 0.f, 0.f, 0.f);
#pragma unroll
        for (int kh = 0; kh < 6; ++kh) {
            if (kh < g) {
                o.x += p[qh][kh] * v4[kh].x; o.y += p[qh][kh] * v4[kh].y;
                o.z += p[qh][kh] * v4[kh].z; o.w += p[qh][kh] * v4[kh].w;
            }
        }
        xrow[qh * 16 + d4] = o;

        // sum over the wave's 4 positions (lane bits 4,5)
        float4 red = o;
#pragma unroll
        for (int m = 16; m <= 32; m <<= 1) {
            float4 tmp = shfl_xor4(red, m);
            red.x += tmp.x; red.y += tmp.y; red.z += tmp.z; red.w += tmp.w;
        }
        if (lane < 16) ((float4*)&psum[wave][qh][0])[d4] = red;
    }
    __syncthreads();

    // combine 4 waves; one atomic per (qh,d) per block
    for (int idx = t; idx < g * 64; idx += 256) {
        int qh = idx >> 6, dd = idx & 63;
        float v = psum[0][qh][dd] + psum[1][qh][dd] + psum[2][qh][dd] + psum[3][qh][dd];
        unsafeAtomicAdd(ws + ((long)(gi * 4 + b) * 8 + qh) * 64 + dd, v);
    }
}

// Pass 2: gather + normalize (r2 version — improved there, kept verbatim).
__global__ __launch_bounds__(256) void k_out(const float* __restrict__ ws,
                                             float* __restrict__ out) {
    const int t = threadIdx.x;
    const int bid = blockIdx.x;
    const int dd4 = t & 15;
    const int h = t >> 4;
    const int b = bid >> 10;           // 1024 position-blocks per batch
    const int pos0 = (bid & 1023) * 8;

    const bool has0 = (h < 6);
    const bool has1 = (h >= 5 && h <= 9);
    const bool has2 = (h >= 10 && h <= 14);

    float4 rs0 = make_float4(1.f, 1.f, 1.f, 1.f), rs1 = rs0, rs2 = rs0;
    if (has0) rs0 = ((const float4*)(ws + ((long)(0 * 4 + b) * 8 + h) * 64))[dd4];
    if (has1) rs1 = ((const float4*)(ws + ((long)(1 * 4 + b) * 8 + (h - 5)) * 64))[dd4];
    if (has2) rs2 = ((const float4*)(ws + ((long)(2 * 4 + b) * 8 + (h - 10)) * 64))[dd4];

    float4 x0[8], x1[4], x2[2];
    if (has0) {
#pragma unroll
        for (int pp = 0; pp < 8; ++pp)
            x0[pp] = ((const float4*)(ws + X0_OFF + (((long)b * 8192 + pos0 + pp) * 6 + h) * 64))[dd4];
    }
    if (has1) {
#pragma unroll
        for (int q = 0; q < 4; ++q) {
            int jj = (pos0 >> 1) + q;
            x1[q] = ((const float4*)(ws + X1_OFF + (((long)b * 4096 + jj) * 5 + (h - 5)) * 64))[dd4];
        }
    }
    if (has2) {
#pragma unroll
        for (int q = 0; q < 2; ++q) {
            int jj = (pos0 >> 2) + q;
            x2[q] = ((const float4*)(ws + X2_OFF + (((long)b * 2048 + jj) * 5 + (h - 10)) * 64))[dd4];
        }
    }

    if (has0) { rs0.x = __frcp_rn(rs0.x); rs0.y = __frcp_rn(rs0.y); rs0.z = __frcp_rn(rs0.z); rs0.w = __frcp_rn(rs0.w); }
    if (has1) { rs1.x = __frcp_rn(rs1.x); rs1.y = __frcp_rn(rs1.y); rs1.z = __frcp_rn(rs1.z); rs1.w = __frcp_rn(rs1.w); }
    if (has2) { rs2.x = __frcp_rn(rs2.x); rs2.y = __frcp_rn(rs2.y); rs2.z = __frcp_rn(rs2.z); rs2.w = __frcp_rn(rs2.w); }

    const float third = 1.0f / 3.0f;
#pragma unroll
    for (int pp = 0; pp < 8; ++pp) {
        float4 r = make_float4(0.f, 0.f, 0.f, 0.f);

        if (has0) {
            r.x += x0[pp].x * rs0.x; r.y += x0[pp].y * rs0.y;
            r.z += x0[pp].z * rs0.z; r.w += x0[pp].w * rs0.w;
        }
        if (has1 && (pp & 1) == 1) {
            int q = pp >> 1;
            r.x += x1[q].x * rs1.x; r.y += x1[q].y * rs1.y;
            r.z += x1[q].z * rs1.z; r.w += x1[q].w * rs1.w;
        }
        if (has2 && (pp & 3) == 2) {
            int q = pp >> 2;
            r.x += x2[q].x * rs2.x; r.y += x2[q].y * rs2.y;
            r.z += x2[q].z * rs2.z; r.w += x2[q].w * rs2.w;
        }

        r.x *= third; r.y *= third; r.z *= third; r.w *= third;
        ((float4*)out)[((long)(b * 8192 + pos0 + pp)) * 256 + t] = r;
    }
}

extern "C" void kernel_launch(void* const* d_in, const int* in_sizes, int n_in,
                              void* d_out, int out_size, void* d_ws, size_t ws_size,
                              hipStream_t stream) {
    const float* Q = (const float*)d_in[0];
    const float* K = (const float*)d_in[1];
    const float* V = (const float*)d_in[2];
    float* ws = (float*)d_ws;
    float* out = (float*)d_out;

    if (ws_size < (size_t)WS_FLOATS * sizeof(float)) return;  // need ~82 MB scratch

    k_zero_sums<<<24, 256, 0, stream>>>(ws);
    k_attn<<<3584, 256, 0, stream>>>(Q, K, V, ws);
    k_out<<<4096, 256, 0, stream>>>(ws, out);
}